// Round 5
// baseline (4077.501 us; speedup 1.0000x reference)
//
#include <hip/hip_runtime.h>
#include <hip/hip_bf16.h>
#include <math.h>
#include <stdint.h>

// ViT config
#define VB   32
#define VS   197
#define VD   768
#define VNH  12
#define VDQ  64
#define VL   12
#define VMLP 3072
#define VC   1000
#define VP   256
#define VNPAT 196
#define VTOK (VB * VS)            // 6304
#define TOKD ((size_t)VTOK * VD)  // 4841472 floats

typedef __attribute__((ext_vector_type(4))) float f32x4;
typedef __attribute__((ext_vector_type(8))) short short8;

typedef __attribute__((address_space(1))) const unsigned int GU;
typedef __attribute__((address_space(3))) unsigned int LU;

__device__ __forceinline__ void gload_lds16(const void* g, void* l) {
    __builtin_amdgcn_global_load_lds((GU*)(uintptr_t)g, (LU*)(uintptr_t)l, 16, 0, 0);
}

// ---------------------------------------------------------------------------
// patchify: X (B,224,224) fp32 -> patches (B*196, 256) bf16
// ---------------------------------------------------------------------------
__global__ void patchify_k(const float* __restrict__ X, __hip_bfloat16* __restrict__ P) {
    int idx = blockIdx.x * 256 + threadIdx.x;
    const int total = VB * VNPAT * VP;
    if (idx >= total) return;
    int i  = idx & 255;
    int p  = (idx >> 8) % VNPAT;
    int b  = (idx >> 8) / VNPAT;
    int pr = p / 14, pc = p % 14;
    int a  = i >> 4, c2 = i & 15;
    P[idx] = __float2bfloat16(X[((size_t)b * 224 + pr * 16 + a) * 224 + pc * 16 + c2]);
}

// ---------------------------------------------------------------------------
// cls token + sinusoidal positional embeddings (x fp32)
// ---------------------------------------------------------------------------
__global__ void pos_cls_k(float* __restrict__ x, const float* __restrict__ cls) {
    size_t idx = (size_t)blockIdx.x * 256 + threadIdx.x;
    if (idx >= TOKD) return;
    int j = (int)(idx % VD);
    int s = (int)((idx / VD) % VS);
    float jj = (float)(j & ~1);
    float freq = expf(-(jj / (float)VD) * 9.2103403719761836f);
    float ang  = (float)s * freq;
    float pe   = (j & 1) ? cosf(ang) : sinf(ang);
    if (s == 0) x[idx] = cls[j] + pe;
    else        x[idx] += pe;
}

// ---------------------------------------------------------------------------
// LayerNorm: x fp32 -> y bf16. One block per token.
// ---------------------------------------------------------------------------
__global__ __launch_bounds__(256) void layernorm_k(
    const float* __restrict__ x, __hip_bfloat16* __restrict__ y,
    const float* __restrict__ g, const float* __restrict__ bta)
{
    int t = blockIdx.x;
    const float* xr = x + (size_t)t * VD;
    __hip_bfloat16* yr = y + (size_t)t * VD;
    int tid = threadIdx.x;
    float v[3];
    float s = 0.f;
    #pragma unroll
    for (int i = 0; i < 3; i++) { v[i] = xr[tid + i * 256]; s += v[i]; }
    __shared__ float red[8];
    #pragma unroll
    for (int off = 32; off; off >>= 1) s += __shfl_xor(s, off);
    int lane = tid & 63, w = tid >> 6;
    if (!lane) red[w] = s;
    __syncthreads();
    float mu = (red[0] + red[1] + red[2] + red[3]) * (1.f / VD);
    float s2 = 0.f;
    #pragma unroll
    for (int i = 0; i < 3; i++) { float d0 = v[i] - mu; s2 += d0 * d0; }
    #pragma unroll
    for (int off = 32; off; off >>= 1) s2 += __shfl_xor(s2, off);
    if (!lane) red[4 + w] = s2;
    __syncthreads();
    float var = (red[4] + red[5] + red[6] + red[7]) * (1.f / VD);
    float rs = rsqrtf(var + 1e-5f);
    #pragma unroll
    for (int i = 0; i < 3; i++) {
        int j = tid + i * 256;
        yr[j] = __float2bfloat16((v[i] - mu) * rs * g[j] + bta[j]);
    }
}

// ---------------------------------------------------------------------------
// Guarded transpose + bf16 convert: in (R,C) fp32 -> out (C,R) bf16.
// ---------------------------------------------------------------------------
__global__ __launch_bounds__(256) void tpose_k(
    const float* __restrict__ in, __hip_bfloat16* __restrict__ out, int R, int C)
{
    __shared__ float t[32][33];
    int c0 = blockIdx.x * 32, r0 = blockIdx.y * 32;
    int tc = threadIdx.x & 31, tr = threadIdx.x >> 5;
    #pragma unroll
    for (int p = 0; p < 4; p++) {
        int r = r0 + tr + p * 8;
        t[tr + p * 8][tc] = (r < R && c0 + tc < C) ? in[(size_t)r * C + c0 + tc] : 0.f;
    }
    __syncthreads();
    #pragma unroll
    for (int p = 0; p < 4; p++) {
        int c = c0 + tr + p * 8;
        if (c < C && r0 + tc < R)
            out[(size_t)c * R + r0 + tc] = __float2bfloat16(t[tc][tr + p * 8]);
    }
}

// ---------------------------------------------------------------------------
// Fused q/k/v weight transpose for one layer: (3 x 12 heads x 768 x 64) fp32
// -> out [2304][768] bf16. grid (2, 24, 36).
// ---------------------------------------------------------------------------
__global__ __launch_bounds__(256) void qkvtp_k(
    const float* __restrict__ Wq, const float* __restrict__ Wk,
    const float* __restrict__ Wv, __hip_bfloat16* __restrict__ out)
{
    __shared__ float t[32][33];
    int z = blockIdx.z;
    int m = z / VNH, h = z % VNH;
    const float* src = (m == 0 ? Wq : m == 1 ? Wk : Wv) + (size_t)h * VD * VDQ;
    __hip_bfloat16* dst = out + ((size_t)m * VD + h * VDQ) * VD;
    int c0 = blockIdx.x * 32, r0 = blockIdx.y * 32;
    int tc = threadIdx.x & 31, tr = threadIdx.x >> 5;
    #pragma unroll
    for (int p = 0; p < 4; p++)
        t[tr + p * 8][tc] = src[(size_t)(r0 + tr + p * 8) * VDQ + c0 + tc];
    __syncthreads();
    #pragma unroll
    for (int p = 0; p < 4; p++)
        dst[(size_t)(c0 + tr + p * 8) * VD + r0 + tc] = __float2bfloat16(t[tc][tr + p * 8]);
}

// combined qkv bias for ALL layers: cb[l][2304]
__global__ void cball_k(const float* __restrict__ bq, const float* __restrict__ bk,
                        const float* __restrict__ bv, float* __restrict__ cb) {
    int idx = blockIdx.x * 256 + threadIdx.x;
    if (idx >= VL * 3 * VD) return;
    int l = idx / (3 * VD), n = idx % (3 * VD);
    int m = n / VD, wi = n % VD;
    const float* p = (m == 0) ? bq : (m == 1) ? bk : bv;
    cb[idx] = p[l * VD + wi];
}

// extract cls rows of x -> bf16 [32][768]
__global__ void cls_k(const float* __restrict__ x, __hip_bfloat16* __restrict__ out) {
    int idx = blockIdx.x * 256 + threadIdx.x;
    if (idx >= VB * VD) return;
    int b = idx / VD, d = idx % VD;
    out[idx] = __float2bfloat16(x[(size_t)b * VS * VD + d]);
}

// ---------------------------------------------------------------------------
// bf16 MFMA GEMM (m97-style 128x128, BK=64, single LDS buffer, 2 barriers)
// — the round-3 kernel, plus Ncols guard so it also serves the head.
// EPI: 0 = fp32 store w/ patch rowmap; 1 = bf16 store; 2 = fp32 accumulate;
//      3 = exact-GELU -> bf16; 4 = plain fp32 store.
// ---------------------------------------------------------------------------
template<int EPI>
__global__ __launch_bounds__(256) void bgemm_k(
    const __hip_bfloat16* __restrict__ A,
    const __hip_bfloat16* __restrict__ BT,
    const float* __restrict__ bias,
    void* __restrict__ Co,
    int M, int K, int ldc, int Ncols)
{
    __shared__ short A_s[128][64];
    __shared__ short B_s[128][64];
    const int tid = threadIdx.x;
    const int w = tid >> 6, l = tid & 63;
    const int row0 = blockIdx.y * 128, col0 = blockIdx.x * 128;
    const int wm = (w >> 1) << 6, wn = (w & 1) << 6;
    f32x4 acc[4][4] = {};

    const int lr = l >> 3;
    const int sslot = (l & 7) ^ lr;
    int arow[4], brow[4];
    #pragma unroll
    for (int i = 0; i < 4; i++) {
        int r = (4 * w + i) * 8 + lr;
        arow[i] = min(row0 + r, M - 1);
        brow[i] = min(col0 + r, Ncols - 1);
    }
    for (int k0 = 0; k0 < K; k0 += 64) {
        __syncthreads();
        #pragma unroll
        for (int i = 0; i < 4; i++) {
            int ch = 4 * w + i;
            gload_lds16((const void*)(A + (size_t)arow[i] * K + k0 + (sslot << 3)),
                        (void*)(&A_s[ch * 8][0]));
            gload_lds16((const void*)(BT + (size_t)brow[i] * K + k0 + (sslot << 3)),
                        (void*)(&B_s[ch * 8][0]));
        }
        __syncthreads();
        #pragma unroll
        for (int ks = 0; ks < 2; ks++) {
            const int s16 = (ks << 2) + (l >> 4);
            short8 av[4], bv[4];
            #pragma unroll
            for (int i = 0; i < 4; i++) {
                int ar = wm + i * 16 + (l & 15);
                av[i] = *(const short8*)((const char*)&A_s[ar][0] + ((s16 ^ (ar & 7)) << 4));
                int br = wn + i * 16 + (l & 15);
                bv[i] = *(const short8*)((const char*)&B_s[br][0] + ((s16 ^ (br & 7)) << 4));
            }
            #pragma unroll
            for (int i = 0; i < 4; i++)
                #pragma unroll
                for (int j = 0; j < 4; j++)
                    acc[i][j] = __builtin_amdgcn_mfma_f32_16x16x32_bf16(av[i], bv[j], acc[i][j], 0, 0, 0);
        }
    }
    const int rbase = row0 + wm + ((l >> 4) << 2);
    const int cbase = col0 + wn + (l & 15);
    #pragma unroll
    for (int i = 0; i < 4; i++) {
        #pragma unroll
        for (int q = 0; q < 4; q++) {
            int rr = rbase + i * 16 + q;
            if (rr >= M) continue;
            #pragma unroll
            for (int j = 0; j < 4; j++) {
                int c = cbase + j * 16;
                if (c >= Ncols) continue;
                float v = acc[i][j][q] + bias[c];
                if (EPI == 0) {
                    int orow = rr + rr / VNPAT + 1;
                    ((float*)Co)[(size_t)orow * ldc + c] = v;
                } else if (EPI == 1) {
                    ((__hip_bfloat16*)Co)[(size_t)rr * ldc + c] = __float2bfloat16(v);
                } else if (EPI == 2) {
                    ((float*)Co)[(size_t)rr * ldc + c] += v;
                } else if (EPI == 3) {
                    float gl = 0.5f * v * (1.f + erff(v * 0.70710678118654752f));
                    ((__hip_bfloat16*)Co)[(size_t)rr * ldc + c] = __float2bfloat16(gl);
                } else {
                    ((float*)Co)[(size_t)rr * ldc + c] = v;
                }
            }
        }
    }
}

// ---------------------------------------------------------------------------
// 256x256 bf16 MFMA GEMM, 512 threads, 8 waves (2M x 4N), per-wave 128x64 out.
// BK=32 slabs, 2-buffer ping-pong in exactly 64 KB static LDS, stage-ahead:
// next slab's global_load_lds issued BEFORE computing current slab, one
// vmcnt(0)+s_barrier per slab (32 MFMA + 12 ds_read_b128 per wave-interval).
// XOR slot swizzle (16B slot ^= (row>>1)&3 in 64B rows) on source AND read.
// Requires: N multiple of 256, K multiple of 32. M clamped.
// EPI: 1 = bf16 store; 3 = exact-GELU -> bf16 store.
// ---------------------------------------------------------------------------
template<int EPI>
__global__ __launch_bounds__(512) void bgemm3_k(
    const __hip_bfloat16* __restrict__ A,
    const __hip_bfloat16* __restrict__ BT,
    const float* __restrict__ bias,
    void* __restrict__ Co,
    int M, int K, int ldc)
{
    __shared__ short As[2][256][32];
    __shared__ short Bs[2][256][32];
    const int tid = threadIdx.x;
    const int w = tid >> 6, l = tid & 63;
    const int fr = l & 15, g = l >> 4;
    const int wr = w >> 2, wc = w & 3;
    const int row0 = blockIdx.y * 256, col0 = blockIdx.x * 256;
    f32x4 acc[8][4] = {};

    // staging: 1024 16B-chunks per matrix per slab; 2 per thread per matrix.
    const __hip_bfloat16* asrc[2];
    const __hip_bfloat16* bsrc[2];
    int dstb[2];
    #pragma unroll
    for (int q = 0; q < 2; q++) {
        int idx = tid + (q << 9);
        int r = idx >> 2, c = idx & 3;
        int s = c ^ ((r >> 1) & 3);                 // pre-swizzled source slot
        asrc[q] = A + (size_t)min(row0 + r, M - 1) * K + (s << 3);
        bsrc[q] = BT + (size_t)(col0 + r) * K + (s << 3);
        dstb[q] = ((tid & ~63) + (q << 9)) << 4;    // wave-uniform dest base
    }

    #define STAGE3(buf, koff)                                                  \
    {                                                                          \
        _Pragma("unroll")                                                      \
        for (int q = 0; q < 2; q++) {                                          \
            gload_lds16(asrc[q] + (koff), (char*)&As[buf][0][0] + dstb[q]);    \
            gload_lds16(bsrc[q] + (koff), (char*)&Bs[buf][0][0] + dstb[q]);    \
        }                                                                      \
    }
    #define COMP3(buf)                                                         \
    {                                                                          \
        short8 bvf[4];                                                         \
        _Pragma("unroll")                                                      \
        for (int ni = 0; ni < 4; ni++) {                                       \
            int br = wc * 64 + ni * 16 + fr;                                   \
            bvf[ni] = *(const short8*)((const char*)&Bs[buf][br][0] +          \
                                       ((g ^ ((br >> 1) & 3)) << 4));          \
        }                                                                      \
        _Pragma("unroll")                                                      \
        for (int mi = 0; mi < 8; mi++) {                                       \
            int ar = wr * 128 + mi * 16 + fr;                                  \
            short8 avf = *(const short8*)((const char*)&As[buf][ar][0] +       \
                                          ((g ^ ((ar >> 1) & 3)) << 4));       \
            _Pragma("unroll")                                                  \
            for (int ni = 0; ni < 4; ni++)                                     \
                acc[mi][ni] = __builtin_amdgcn_mfma_f32_16x16x32_bf16(         \
                    avf, bvf[ni], acc[mi][ni], 0, 0, 0);                       \
        }                                                                      \
    }

    const int nt = K >> 5;
    STAGE3(0, 0);
    asm volatile("s_waitcnt vmcnt(0)" ::: "memory");
    __builtin_amdgcn_s_barrier();
    __builtin_amdgcn_sched_barrier(0);
    for (int t = 0; t < nt; t++) {
        if (t + 1 < nt) STAGE3((t + 1) & 1, (t + 1) << 5);
        COMP3(t & 1);
        asm volatile("s_waitcnt vmcnt(0)" ::: "memory");
        __builtin_amdgcn_s_barrier();
        __builtin_amdgcn_sched_barrier(0);
    }
    #undef STAGE3
    #undef COMP3

    const int rb = row0 + wr * 128 + (g << 2);
    const int cb = col0 + wc * 64 + fr;
    #pragma unroll
    for (int mi = 0; mi < 8; mi++) {
        #pragma unroll
        for (int qi = 0; qi < 4; qi++) {
            int rr = rb + mi * 16 + qi;
            if (rr >= M) continue;
            #pragma unroll
            for (int ni = 0; ni < 4; ni++) {
                int c = cb + ni * 16;
                float v = acc[mi][ni][qi] + bias[c];
                if (EPI == 1) {
                    ((__hip_bfloat16*)Co)[(size_t)rr * ldc + c] = __float2bfloat16(v);
                } else {
                    float gl = 0.5f * v * (1.f + erff(v * 0.70710678118654752f));
                    ((__hip_bfloat16*)Co)[(size_t)rr * ldc + c] = __float2bfloat16(gl);
                }
            }
        }
    }
}

// ---------------------------------------------------------------------------
// MFMA attention (unchanged). One block per (b,h), 4 waves.
// ---------------------------------------------------------------------------
__device__ __forceinline__ int swz_idx(int row, int k) {
    return row * 256 + (((k >> 3) ^ (row & 7)) << 3) + (k & 7);
}
__device__ __forceinline__ unsigned pack_bf16(float a, float b) {
    __hip_bfloat16 x = __float2bfloat16(a), y = __float2bfloat16(b);
    unsigned short ux = *(unsigned short*)&x, uy = *(unsigned short*)&y;
    return (unsigned)ux | ((unsigned)uy << 16);
}

__global__ __launch_bounds__(256) void attn3_k(
    const __hip_bfloat16* __restrict__ qkv, __hip_bfloat16* __restrict__ o)
{
    __shared__ short V_t[64 * 256];
    __shared__ short P_s[4][16 * 256];
    const int bh = blockIdx.x;
    const int b = bh / VNH, h = bh % VNH;
    const int tid = threadIdx.x, w = tid >> 6, l = tid & 63;
    const int g = l >> 4, c16 = l & 15;

    const __hip_bfloat16* base = qkv + (size_t)(b * VS) * (3 * VD) + h * VDQ;

    {
        const __hip_bfloat16* vbase = base + 2 * VD;
        int t = tid & 31, e0 = (tid >> 5) * 8;
        #pragma unroll
        for (int it = 0; it < 7; it++) {
            int tt = it * 32 + t;
            if (tt < VS) {
                short8 vv = *(const short8*)(vbase + (size_t)tt * (3 * VD) + e0);
                #pragma unroll
                for (int j = 0; j < 8; j++) V_t[swz_idx(e0 + j, tt)] = vv[j];
            }
        }
        for (int idx = tid; idx < 64 * 27; idx += 256) {
            int e = idx / 27, k = 197 + idx % 27;
            V_t[swz_idx(e, k)] = 0;
        }
    }
    {
        unsigned* p0 = (unsigned*)&P_s[w][swz_idx(c16, 208 + g * 4)];
        p0[0] = 0; p0[1] = 0;
    }
    __syncthreads();

    for (int qt = w; qt < 13; qt += 4) {
        const int q0 = qt * 16;
        int qr = min(q0 + c16, VS - 1);
        const __hip_bfloat16* qp = base + (size_t)qr * (3 * VD) + g * 8;
        short8 qa0 = *(const short8*)(qp);
        short8 qa1 = *(const short8*)(qp + 32);

        f32x4 st[13];
        #pragma unroll
        for (int t = 0; t < 13; t++) {
            int kr = min(t * 16 + c16, VS - 1);
            const __hip_bfloat16* kp = base + VD + (size_t)kr * (3 * VD) + g * 8;
            short8 ka0 = *(const short8*)(kp);
            short8 ka1 = *(const short8*)(kp + 32);
            f32x4 z = {};
            z = __builtin_amdgcn_mfma_f32_16x16x32_bf16(ka0, qa0, z, 0, 0, 0);
            z = __builtin_amdgcn_mfma_f32_16x16x32_bf16(ka1, qa1, z, 0, 0, 0);
            st[t] = z;
        }
        #pragma unroll
        for (int t = 0; t < 13; t++) {
            #pragma unroll
            for (int r = 0; r < 4; r++) {
                float v = st[t][r] * 0.125f;
                if (t == 12 && (4 * g + r) >= 5) v = -3.0e38f;
                st[t][r] = v;
            }
        }
        float m = -3.0e38f;
        #pragma unroll
        for (int t = 0; t < 13; t++)
            #pragma unroll
            for (int r = 0; r < 4; r++) m = fmaxf(m, st[t][r]);
        m = fmaxf(m, __shfl_xor(m, 16));
        m = fmaxf(m, __shfl_xor(m, 32));
        float sum = 0.f;
        #pragma unroll
        for (int t = 0; t < 13; t++)
            #pragma unroll
            for (int r = 0; r < 4; r++) { float e = expf(st[t][r] - m); st[t][r] = e; sum += e; }
        sum += __shfl_xor(sum, 16);
        sum += __shfl_xor(sum, 32);
        float inv = 1.f / sum;
        #pragma unroll
        for (int t = 0; t < 13; t++) {
            int k0 = 16 * t + 4 * g;
            unsigned* pp = (unsigned*)&P_s[w][swz_idx(c16, k0)];
            pp[0] = pack_bf16(st[t][0] * inv, st[t][1] * inv);
            pp[1] = pack_bf16(st[t][2] * inv, st[t][3] * inv);
        }
        f32x4 acc[4] = {};
        #pragma unroll
        for (int ki = 0; ki < 7; ki++) {
            int k0 = ki * 32 + g * 8;
            short8 pa = *(const short8*)&P_s[w][swz_idx(c16, k0)];
            #pragma unroll
            for (int et = 0; et < 4; et++) {
                short8 vbf = *(const short8*)&V_t[swz_idx(et * 16 + c16, k0)];
                acc[et] = __builtin_amdgcn_mfma_f32_16x16x32_bf16(pa, vbf, acc[et], 0, 0, 0);
            }
        }
        #pragma unroll
        for (int et = 0; et < 4; et++) {
            #pragma unroll
            for (int r = 0; r < 4; r++) {
                int q = q0 + 4 * g + r;
                if (q < VS)
                    o[((size_t)(b * VS) + q) * VD + h * VDQ + et * 16 + c16] =
                        __float2bfloat16(acc[et][r]);
            }
        }
    }
}

// ---------------------------------------------------------------------------
extern "C" void kernel_launch(void* const* d_in, const int* in_sizes, int n_in,
                              void* d_out, int out_size, void* d_ws, size_t ws_size,
                              hipStream_t stream) {
    (void)in_sizes; (void)n_in; (void)out_size; (void)ws_size;
    const float* X       = (const float*)d_in[0];
    const float* patch_W = (const float*)d_in[1];
    const float* patch_b = (const float*)d_in[2];
    const float* cls_tok = (const float*)d_in[3];
    const float* ln1_g   = (const float*)d_in[4];
    const float* ln1_b   = (const float*)d_in[5];
    const float* Wq      = (const float*)d_in[6];
    const float* bq      = (const float*)d_in[7];
    const float* Wk      = (const float*)d_in[8];
    const float* bk      = (const float*)d_in[9];
    const float* Wv      = (const float*)d_in[10];
    const float* bv      = (const float*)d_in[11];
    const float* proj_W  = (const float*)d_in[12];
    const float* proj_b  = (const float*)d_in[13];
    const float* ln2_g   = (const float*)d_in[14];
    const float* ln2_b   = (const float*)d_in[15];
    const float* mlp_W1  = (const float*)d_in[16];
    const float* mlp_b1  = (const float*)d_in[17];
    const float* mlp_W2  = (const float*)d_in[18];
    const float* mlp_b2  = (const float*)d_in[19];
    const float* head_W  = (const float*)d_in[20];
    const float* head_b  = (const float*)d_in[21];

    char* ws = (char*)d_ws;
    float*          x   = (float*)ws;                             // 19.37 MB fp32
    __hip_bfloat16* tb  = (__hip_bfloat16*)(ws + 19365888);       // 9.68 MB bf16
    __hip_bfloat16* big = (__hip_bfloat16*)(ws + 29048832);       // 38.73 MB
    __hip_bfloat16* wT  = (__hip_bfloat16*)(ws + 67780608);       // 4.72 MB
    float*          cbA = (float*)(ws + 72499200);                // 110 KB (12x2304)

    cball_k<<<(VL * 3 * VD + 255) / 256, 256, 0, stream>>>(bq, bk, bv, cbA);

    patchify_k<<<(VB * VNPAT * VP + 255) / 256, 256, 0, stream>>>(X, big);
    {
        dim3 g(VD / 32, VP / 32);
        tpose_k<<<g, 256, 0, stream>>>(patch_W, wT, VP, VD);
    }
    {
        dim3 g(VD / 128, VB * VNPAT / 128);
        bgemm_k<0><<<g, 256, 0, stream>>>(big, wT, patch_b, x, VB * VNPAT, VP, VD, VD);
    }
    pos_cls_k<<<(unsigned)((TOKD + 255) / 256), 256, 0, stream>>>(x, cls_tok);

    const size_t WSZ = (size_t)VNH * VD * VDQ;
    for (int l = 0; l < VL; l++) {
        layernorm_k<<<VTOK, 256, 0, stream>>>(x, tb, ln1_g + l * VD, ln1_b + l * VD);

        {
            dim3 g(2, 24, 36);
            qkvtp_k<<<g, 256, 0, stream>>>(Wq + l * WSZ, Wk + l * WSZ, Wv + l * WSZ, wT);
        }
        {
            // fused QKV GEMM: 256x256 tiles, (2304/256=9) x ceil(6304/256=25)
            dim3 g(3 * VD / 256, (VTOK + 255) / 256);
            bgemm3_k<1><<<g, 512, 0, stream>>>(tb, wT, cbA + l * 3 * VD, big,
                                               VTOK, VD, 3 * VD);
        }
        attn3_k<<<VB * VNH, 256, 0, stream>>>(big, tb);

        {
            dim3 gt(VD / 32, VD / 32);
            tpose_k<<<gt, 256, 0, stream>>>(proj_W + (size_t)l * VD * VD, wT, VD, VD);
            dim3 g(VD / 128, (VTOK + 127) / 128);
            bgemm_k<2><<<g, 256, 0, stream>>>(tb, wT, proj_b + l * VD, x,
                                              VTOK, VD, VD, VD);
        }
        layernorm_k<<<VTOK, 256, 0, stream>>>(x, tb, ln2_g + l * VD, ln2_b + l * VD);
        {
            dim3 gt(VMLP / 32, VD / 32);
            tpose_k<<<gt, 256, 0, stream>>>(mlp_W1 + (size_t)l * VD * VMLP, wT, VD, VMLP);
            // MLP1: 256x256 tiles, (3072/256=12) x 25
            dim3 g(VMLP / 256, (VTOK + 255) / 256);
            bgemm3_k<3><<<g, 512, 0, stream>>>(tb, wT, mlp_b1 + l * VMLP, big,
                                               VTOK, VD, VMLP);
        }
        {
            dim3 gt(VD / 32, VMLP / 32);
            tpose_k<<<gt, 256, 0, stream>>>(mlp_W2 + (size_t)l * VMLP * VD, wT, VMLP, VD);
            dim3 g(VD / 128, (VTOK + 127) / 128);
            bgemm_k<2><<<g, 256, 0, stream>>>(big, wT, mlp_b2 + l * VD, x,
                                              VTOK, VMLP, VD, VD);
        }
    }
    // head: cls rows -> bf16, transpose head_W, 128^2 MFMA GEMM with N-guard
    cls_k<<<(VB * VD + 255) / 256, 256, 0, stream>>>(x, tb);
    {
        dim3 gt((VC + 31) / 32, VD / 32);
        tpose_k<<<gt, 256, 0, stream>>>(head_W, wT, VD, VC);
        dim3 g((VC + 127) / 128, 1);
        bgemm_k<4><<<g, 256, 0, stream>>>(tb, wT, head_b, (float*)d_out,
                                          VB, VD, VC, VC);
    }
}